// Round 6
// baseline (1147.163 us; speedup 1.0000x reference)
//
#include <hip/hip_runtime.h>

#define NB 64
#define NC 32
#define NH 16
#define NW 16
#define NE 4096
#define NTOT (NB*NC*NH*NW)   // 524288
#define IDXW 341             // 1+4+16+64+256
#define PHI_BLOCKS_TOTAL 2560  // 5 scales * 512

__device__ __forceinline__ double cubicw(double x) {
  const double A = -0.75;
  x = fabs(x);
  if (x <= 1.0) return ((A + 2.0) * x - (A + 3.0)) * x * x + 1.0;
  if (x < 2.0)  return A * (((x - 5.0) * x + 8.0) * x - 4.0);
  return 0.0;
}

// setup: z_res init (all 2048 blocks) + emb transpose + emb_sq (blocks 0..63)
__global__ void k_setup(const float* __restrict__ z, const float* __restrict__ emb,
                        double* __restrict__ z_res, float* __restrict__ emb_t,
                        double* __restrict__ emb_sq, double* __restrict__ loss_d,
                        unsigned* __restrict__ counter) {
  __shared__ float tile[64][33];
  int tid = threadIdx.x;
  int i = blockIdx.x * 256 + tid;
  if (i < NTOT) z_res[i] = (double)z[i];
  if (i == 0) { *loss_d = 0.0; *counter = 0u; }
  if (blockIdx.x < 64) {
    int e0 = blockIdx.x * 64;
    #pragma unroll
    for (int i2 = 0; i2 < 8; i2++) {
      int t = i2 * 256 + tid;
      int el = t >> 5, c = t & 31;
      tile[el][c] = emb[(e0 + el) * NC + c];
    }
    __syncthreads();
    #pragma unroll
    for (int i2 = 0; i2 < 8; i2++) {
      int t = i2 * 256 + tid;
      int c = t >> 6, ep = t & 63;
      emb_t[c * NE + e0 + ep] = tile[ep][c];
    }
    if (tid < 64) {
      const float* tr = &tile[tid][0];
      double s = 0.0;
      #pragma unroll
      for (int j = 0; j < 8; j++) {
        s += (double)tr[4*j] * tr[4*j] + (double)tr[4*j+1] * tr[4*j+1]
           + (double)tr[4*j+2] * tr[4*j+2] + (double)tr[4*j+3] * tr[4*j+3];
      }
      emb_sq[e0 + tid] = s;
    }
  }
}

// nearest-codebook search with fused area-pooling.
// rv[j][c] = mean over f x f block of z_res (sequential dy/dx sum — matches np
// within fp64 chain; identical to the previously-passing k_pool order).
#define ROWS 8
#define EV 4
__global__ void k_argmin(const double* __restrict__ z_res, const float* __restrict__ emb_t,
                         const double* __restrict__ emb_sq, int ph, int f,
                         int* __restrict__ idx_ws, float* __restrict__ out_idx,
                         int idx_off) {
  __shared__ double rv[ROWS][NC];
  __shared__ double wd[4][ROWS];
  __shared__ int    wi[4][ROWS];
  int tid = threadIdx.x;
  int row0 = blockIdx.x * ROWS;
  {
    int j = tid >> 5, c = tid & 31;   // 256 = 8*32 exactly
    int n = row0 + j;
    int x = n % ph, y = (n / ph) % ph, b = n / (ph * ph);
    const double* base = z_res + (((b * NC + c) * NH) + y * f) * NW + x * f;
    double s = 0.0;
    for (int dy = 0; dy < f; dy++)
      for (int dx = 0; dx < f; dx++) s += base[dy * NW + dx];
    rv[j][c] = s / (double)(f * f);
  }
  __syncthreads();
  double best[ROWS]; int bidx[ROWS];
  #pragma unroll
  for (int j = 0; j < ROWS; j++) { best[j] = 1e300; bidx[j] = 0; }
  for (int it = 0; it < NE / (256 * EV); ++it) {   // 4 chunks
    int e0 = it * (256 * EV) + tid * EV;
    double acc[ROWS][EV];
    #pragma unroll
    for (int j = 0; j < ROWS; j++)
      #pragma unroll
      for (int v = 0; v < EV; v++) acc[j][v] = 0.0;
    #pragma unroll 4
    for (int k = 0; k < NC; k++) {
      float4 e4 = *(const float4*)(emb_t + k * NE + e0);  // coalesced 16B/lane
      double d0 = e4.x, d1 = e4.y, d2 = e4.z, d3 = e4.w;
      #pragma unroll
      for (int j = 0; j < ROWS; j++) {
        double rj = rv[j][k];
        acc[j][0] += rj * d0; acc[j][1] += rj * d1;
        acc[j][2] += rj * d2; acc[j][3] += rj * d3;
      }
    }
    #pragma unroll
    for (int v = 0; v < EV; v++) {     // v ascending: lowest e kept on ties
      double esq = emb_sq[e0 + v];
      #pragma unroll
      for (int j = 0; j < ROWS; j++) {
        double d = esq - 2.0 * acc[j][v];
        if (d < best[j]) { best[j] = d; bidx[j] = e0 + v; }
      }
    }
  }
  #pragma unroll
  for (int j = 0; j < ROWS; j++) {
    double d = best[j]; int bi2 = bidx[j];
    #pragma unroll
    for (int off = 32; off >= 1; off >>= 1) {
      double od = __shfl_xor(d, off, 64);
      int oi = __shfl_xor(bi2, off, 64);
      if (od < d || (od == d && oi < bi2)) { d = od; bi2 = oi; }
    }
    best[j] = d; bidx[j] = bi2;
  }
  int wave = tid >> 6, lane = tid & 63;
  if (lane == 0) {
    #pragma unroll
    for (int j = 0; j < ROWS; j++) { wd[wave][j] = best[j]; wi[wave][j] = bidx[j]; }
  }
  __syncthreads();
  if (tid < ROWS) {
    double d = wd[0][tid]; int bi2 = wi[0][tid];
    #pragma unroll
    for (int w2 = 1; w2 < 4; w2++) {
      double od = wd[w2][tid]; int oi = wi[w2][tid];
      if (od < d || (od == d && oi < bi2)) { d = od; bi2 = oi; }
    }
    int n = row0 + tid;
    idx_ws[n] = bi2;
    int x = n % ph, y = (n / ph) % ph, b = n / (ph * ph);
    out_idx[b * IDXW + idx_off + y * ph + x] = (float)bi2;
  }
}

// fused gather + bicubic_h + bicubic_w, one block per image, dynamic LDS.
// ph==16: pure gather. Math expressions identical to the split kernels.
__global__ void k_upsample(const int* __restrict__ idx_ws, const float* __restrict__ emb,
                           double* __restrict__ q, int ph) {
  extern __shared__ double lds[];
  int b = blockIdx.x;
  int tid = threadIdx.x;
  if (ph == 16) {
    for (int i = tid; i < NC * 256; i += 256) {
      int c = i >> 8, rem = i & 255;
      q[b * NC * 256 + i] = (double)emb[idx_ws[b * 256 + rem] * NC + c];
    }
    return;
  }
  double* qs = lds;                  // [NC][ph][ph]
  double* tt = lds + NC * ph * ph;   // [NC][16][ph]
  for (int i = tid; i < NC * ph * ph; i += 256) {
    int c = i / (ph * ph), rem = i % (ph * ph);
    int y = rem / ph, x = rem % ph;
    qs[i] = (double)emb[idx_ws[(b * ph + y) * ph + x] * NC + c];
  }
  __syncthreads();
  double scale = (double)ph / 16.0;
  for (int i = tid; i < NC * 16 * ph; i += 256) {
    int x = i % ph; int oy = (i / ph) % 16; int c = i / (16 * ph);
    double src = ((double)oy + 0.5) * scale - 0.5;
    double fi = floor(src);
    int i0 = (int)fi;
    double frac = src - fi;
    double s = 0.0;
    #pragma unroll
    for (int k = 0; k < 4; k++) {
      int iy = min(max(i0 + k - 1, 0), ph - 1);
      s += cubicw(frac - (double)(k - 1)) * qs[(c * ph + iy) * ph + x];
    }
    tt[i] = s;
  }
  __syncthreads();
  for (int i = tid; i < NC * 256; i += 256) {
    int ox = i & 15; int oy = (i >> 4) & 15; int c = i >> 8;
    double src = ((double)ox + 0.5) * scale - 0.5;
    double fi = floor(src);
    int i0 = (int)fi;
    double frac = src - fi;
    double s = 0.0;
    #pragma unroll
    for (int k = 0; k < 4; k++) {
      int ix = min(max(i0 + k - 1, 0), ph - 1);
      s += cubicw(frac - (double)(k - 1)) * tt[(c * 16 + oy) * ph + ix];
    }
    q[b * NC * 256 + i] = s;
  }
}

// Phi + residual update + loss. z_hat == z - z_res (no separate z_hat buffer).
// Last phi block across all 5 dispatches finalizes the loss scalar.
__global__ __launch_bounds__(256) void k_phi_update(
    const double* __restrict__ q, const float* __restrict__ w,
    const float* __restrict__ bias, const float* __restrict__ z,
    double* __restrict__ z_res, float* __restrict__ out_zhat,
    double* __restrict__ loss_d, unsigned* __restrict__ counter,
    float* __restrict__ out_loss, int last) {
  __shared__ double simg[NC * NH * NW];  // 64 KB
  int b = blockIdx.x >> 3;
  int co0 = (blockIdx.x & 7) * 4;
  int tid = threadIdx.x;
  const double* qb = q + b * NC * NH * NW;
  for (int i = tid; i < NC * NH * NW; i += 256) simg[i] = qb[i];
  __syncthreads();
  int x = tid & 15, y = tid >> 4;
  double acc[4] = {0.0, 0.0, 0.0, 0.0};
  for (int ci = 0; ci < NC; ci++) {
    double wv[9];
    #pragma unroll
    for (int ky = 0; ky < 3; ky++) {
      int yy = y + ky - 1;
      #pragma unroll
      for (int kx = 0; kx < 3; kx++) {
        int xx = x + kx - 1;
        wv[ky * 3 + kx] = (yy >= 0 && yy < NH && xx >= 0 && xx < NW)
                          ? simg[ci * 256 + yy * 16 + xx] : 0.0;
      }
    }
    #pragma unroll
    for (int j = 0; j < 4; j++) {
      const float* wp = w + ((co0 + j) * NC + ci) * 9;  // uniform -> s_loads
      double a = acc[j];
      #pragma unroll
      for (int k = 0; k < 9; k++) a += wv[k] * (double)wp[k];
      acc[j] = a;
    }
  }
  double lsum = 0.0;
  #pragma unroll
  for (int j = 0; j < 4; j++) {
    int co = co0 + j;
    int i = co * 256 + tid;
    int gi = b * NC * NH * NW + i;
    double val = simg[i] * 0.5 + (acc[j] + (double)bias[co]) * 0.5;
    double zr = z_res[gi] - val;
    z_res[gi] = zr;
    if (last) out_zhat[gi] = (float)((double)z[gi] - zr);
    lsum += zr * zr;    // z_hat - z == -z_res (within fp64 rounding; loss thr loose)
  }
  __syncthreads();              // done with simg contents
  double* red = simg;           // reuse LDS for reduction
  red[tid] = lsum; __syncthreads();
  for (int s = 128; s > 0; s >>= 1) {
    if (tid < s) red[tid] += red[tid + s];
    __syncthreads();
  }
  if (tid == 0) {
    atomicAdd(loss_d, red[0]);
    __threadfence();
    unsigned old = atomicAdd(counter, 1u);
    if (old == PHI_BLOCKS_TOTAL - 1) {
      double tot = atomicAdd(loss_d, 0.0);  // atomic read: all adds visible
      *out_loss = (float)(tot * (1.25 / (5.0 * (double)NTOT)));
    }
  }
}

extern "C" void kernel_launch(void* const* d_in, const int* in_sizes, int n_in,
                              void* d_out, int out_size, void* d_ws, size_t ws_size,
                              hipStream_t stream) {
  const float* z     = (const float*)d_in[0];   // [64,32,16,16]
  const float* emb   = (const float*)d_in[1];   // [4096,32]
  const float* phi_w = (const float*)d_in[2];   // [4,32,32,3,3]
  const float* phi_b = (const float*)d_in[3];   // [4,32]

  float* out      = (float*)d_out;
  float* out_zhat = out;
  float* out_loss = out + NTOT;
  float* out_idx  = out + NTOT + 1; // [64,341] as floats

  double* ws        = (double*)d_ws;
  double* z_res     = ws;                        // 524288 f64
  double* q         = z_res + NTOT;              // 524288 f64
  double* emb_sq    = q + NTOT;                  // 4096 f64
  double* loss_d    = emb_sq + NE;               // 1 f64
  float* emb_t      = (float*)(loss_d + 1);      // 131072 f32
  int* idx_ws       = (int*)(emb_t + NE * NC);   // 16384 int
  unsigned* counter = (unsigned*)(idx_ws + NB * 256);

  k_setup<<<NTOT / 256, 256, 0, stream>>>(z, emb, z_res, emb_t, emb_sq, loss_d, counter);

  const int phs[5]  = {1, 2, 4, 8, 16};
  // Phi tick selection: ticks = np.linspace(1/12, 11/12, 4) in float64.
  // si=2 is an exact tie in real arithmetic, but f64 linspace rounding makes
  // |ticks[2]-0.5| smaller by 2 ulps -> pi=2 (verified by exact mantissa calc).
  const int pis[5]  = {0, 1, 2, 2, 3};
  const int offs[5] = {0, 1, 5, 21, 85};

  for (int si = 0; si < 5; si++) {
    int ph = phs[si];
    int f = NH / ph;
    int nrows = NB * ph * ph;
    k_argmin<<<nrows / ROWS, 256, 0, stream>>>(z_res, emb_t, emb_sq, ph, f,
                                               idx_ws, out_idx, offs[si]);
    size_t lds_bytes = (si != 4) ? (size_t)(NC * ph * ph + NC * 16 * ph) * 8 : 0;
    k_upsample<<<NB, 256, lds_bytes, stream>>>(idx_ws, emb, q, ph);
    k_phi_update<<<NB * 8, 256, 0, stream>>>(q, phi_w + pis[si] * NC * NC * 9,
                                             phi_b + pis[si] * NC, z, z_res,
                                             out_zhat, loss_d, counter, out_loss,
                                             si == 4 ? 1 : 0);
  }
}

// Round 8
// 997.171 us; speedup vs baseline: 1.1504x; 1.1504x over previous
//
#include <hip/hip_runtime.h>

#define NB 64
#define NC 32
#define NH 16
#define NW 16
#define NE 4096
#define NTOT (NB*NC*NH*NW)   // 524288
#define IDXW 341             // 1+4+16+64+256
#define GRID 256
#define TPB 256
#define NBAR 16

__device__ __forceinline__ double cubicw(double x) {
  const double A = -0.75;
  x = fabs(x);
  if (x <= 1.0) return ((A + 2.0) * x - (A + 3.0)) * x * x + 1.0;
  if (x < 2.0)  return A * (((x - 5.0) * x + 8.0) * x - 4.0);
  return 0.0;
}

// One-shot software grid barrier (one counter per barrier, never reused).
// All GRID blocks are co-resident (1 block/CU, 64 KB LDS, 256-CU device).
__device__ __forceinline__ void gridbar(unsigned* bar) {
  __syncthreads();
  if (threadIdx.x == 0) {
    __threadfence();                       // release (agent fence: L2 wb cross-XCD)
    atomicAdd(bar, 1u);
    while (atomicAdd(bar, 0u) < (unsigned)GRID) __builtin_amdgcn_s_sleep(2);
    __threadfence();                       // acquire (invalidate stale)
  }
  __syncthreads();
}

__global__ __launch_bounds__(TPB) void k_fused(
    const float* __restrict__ z, const float* __restrict__ emb,
    const float* __restrict__ phi_w, const float* __restrict__ phi_b,
    double* __restrict__ z_res, double* __restrict__ q,
    double* __restrict__ emb_sq, double* __restrict__ loss_d,
    float* __restrict__ emb_t, int* __restrict__ idx_ws,
    unsigned* __restrict__ bars,
    float* __restrict__ out_zhat, float* __restrict__ out_loss,
    float* __restrict__ out_idx)
{
  __shared__ double lds[8192];   // 64 KB scratch, reused per phase
  const int tid = threadIdx.x;
  const int bid = blockIdx.x;

  // Barrier counters arrive poisoned (0xAA); idempotent CAS-init by every block
  // BEFORE any barrier use. Counters never revisit the poison value.
  if (tid < NBAR) atomicCAS(&bars[tid], 0xAAAAAAAAu, 0u);
  __syncthreads();
  int bar_i = 0;

  // ---------- setup: z_res init + emb transpose + emb_sq ----------
  for (int i = bid * TPB + tid; i < NTOT; i += GRID * TPB)
    z_res[i] = (double)z[i];
  if (bid == 0 && tid == 0) *loss_d = 0.0;
  if (bid < 64) {
    float* tile = (float*)lds;            // [64][33]
    int e0 = bid * 64;
    #pragma unroll
    for (int i2 = 0; i2 < 8; i2++) {
      int t = i2 * 256 + tid;
      int el = t >> 5, c = t & 31;
      tile[el * 33 + c] = emb[(e0 + el) * NC + c];
    }
    __syncthreads();
    #pragma unroll
    for (int i2 = 0; i2 < 8; i2++) {
      int t = i2 * 256 + tid;
      int c = t >> 6, ep = t & 63;
      emb_t[c * NE + e0 + ep] = tile[ep * 33 + c];
    }
    if (tid < 64) {
      const float* tr = &tile[tid * 33];
      double s = 0.0;
      #pragma unroll
      for (int j = 0; j < 8; j++)
        s += (double)tr[4*j]*tr[4*j] + (double)tr[4*j+1]*tr[4*j+1]
           + (double)tr[4*j+2]*tr[4*j+2] + (double)tr[4*j+3]*tr[4*j+3];
      emb_sq[e0 + tid] = s;
    }
  }
  gridbar(&bars[bar_i++]);

  const int phs[5]  = {1, 2, 4, 8, 16};
  // ticks = np.linspace(1/12, 11/12, 4) f64: si=2 real-arithmetic tie breaks
  // to pi=2 via 2-ulp linspace rounding (verified by exact mantissa calc).
  const int pis[5]  = {0, 1, 2, 2, 3};
  const int offs[5] = {0, 1, 5, 21, 85};

  for (int si = 0; si < 5; si++) {
    const int ph = phs[si], f = NH / ph;
    const int idx_off = offs[si];

    // ---------- argmin (fused area-pool, fp64 distances) ----------
    {
      double* rv = lds;                   // [8][32]
      double* wd = rv + 8 * NC;           // [4][8]
      int*    wi = (int*)(wd + 32);       // [4][8]
      int nchunks = (NB * ph * ph) >> 3;  // rows / 8
      for (int chunk = bid; chunk < nchunks; chunk += GRID) {
        int row0 = chunk * 8;
        {
          int j = tid >> 5, c = tid & 31;   // 256 = 8*32
          int n = row0 + j;
          int x = n % ph, y = (n / ph) % ph, b = n / (ph * ph);
          const double* base = z_res + (((b * NC + c) * NH) + y * f) * NW + x * f;
          double s = 0.0;
          for (int dy = 0; dy < f; dy++)
            for (int dx = 0; dx < f; dx++) s += base[dy * NW + dx];
          rv[j * NC + c] = s / (double)(f * f);
        }
        __syncthreads();
        double best[8]; int bidx[8];
        #pragma unroll
        for (int j = 0; j < 8; j++) { best[j] = 1e300; bidx[j] = 0; }
        for (int it = 0; it < NE / 1024; ++it) {   // 4 chunks of 1024 entries
          int e0 = it * 1024 + tid * 4;
          double acc[8][4];
          #pragma unroll
          for (int j = 0; j < 8; j++)
            #pragma unroll
            for (int v = 0; v < 4; v++) acc[j][v] = 0.0;
          #pragma unroll 4
          for (int k = 0; k < NC; k++) {
            float4 e4 = *(const float4*)(emb_t + k * NE + e0);
            double d0 = e4.x, d1 = e4.y, d2 = e4.z, d3 = e4.w;
            #pragma unroll
            for (int j = 0; j < 8; j++) {
              double rj = rv[j * NC + k];
              acc[j][0] += rj * d0; acc[j][1] += rj * d1;
              acc[j][2] += rj * d2; acc[j][3] += rj * d3;
            }
          }
          #pragma unroll
          for (int v = 0; v < 4; v++) {      // v ascending: lowest e on ties
            double esq = emb_sq[e0 + v];
            #pragma unroll
            for (int j = 0; j < 8; j++) {
              double d = esq - 2.0 * acc[j][v];
              if (d < best[j]) { best[j] = d; bidx[j] = e0 + v; }
            }
          }
        }
        #pragma unroll
        for (int j = 0; j < 8; j++) {
          double d = best[j]; int bi2 = bidx[j];
          #pragma unroll
          for (int off = 32; off >= 1; off >>= 1) {
            double od = __shfl_xor(d, off, 64);
            int oi = __shfl_xor(bi2, off, 64);
            if (od < d || (od == d && oi < bi2)) { d = od; bi2 = oi; }
          }
          best[j] = d; bidx[j] = bi2;
        }
        int wave = tid >> 6, lane = tid & 63;
        if (lane == 0) {
          #pragma unroll
          for (int j = 0; j < 8; j++) { wd[wave * 8 + j] = best[j]; wi[wave * 8 + j] = bidx[j]; }
        }
        __syncthreads();
        if (tid < 8) {
          double d = wd[tid]; int bi2 = wi[tid];
          #pragma unroll
          for (int w2 = 1; w2 < 4; w2++) {
            double od = wd[w2 * 8 + tid]; int oi = wi[w2 * 8 + tid];
            if (od < d || (od == d && oi < bi2)) { d = od; bi2 = oi; }
          }
          int n = row0 + tid;
          idx_ws[n] = bi2;
          int x = n % ph, y = (n / ph) % ph, b = n / (ph * ph);
          out_idx[b * IDXW + idx_off + y * ph + x] = (float)bi2;
        }
        __syncthreads();   // rv/wd/wi reused next chunk iteration
      }
    }
    gridbar(&bars[bar_i++]);

    // ---------- upsample: gather + bicubic H + W (8 channels per block) ----------
    {
      int b = bid >> 2, c0 = (bid & 3) * 8;
      if (ph == 16) {
        for (int i = tid; i < 8 * 256; i += 256) {
          int j = i >> 8, rem = i & 255;
          q[(b * NC + c0 + j) * 256 + rem] = (double)emb[idx_ws[b * 256 + rem] * NC + c0 + j];
        }
      } else {
        double* qs = lds;                  // [8][ph][ph]   (ph<=8: <=4 KB)
        double* tt = qs + 8 * ph * ph;     // [8][16][ph]   (ph<=8: <=8 KB)
        for (int i = tid; i < 8 * ph * ph; i += 256) {
          int j = i / (ph * ph), rem = i % (ph * ph);
          int y = rem / ph, x = rem % ph;
          qs[i] = (double)emb[idx_ws[(b * ph + y) * ph + x] * NC + c0 + j];
        }
        __syncthreads();
        double scale = (double)ph / 16.0;
        for (int i = tid; i < 8 * 16 * ph; i += 256) {
          int x = i % ph; int oy = (i / ph) % 16; int j = i / (16 * ph);
          double src = ((double)oy + 0.5) * scale - 0.5;
          double fi = floor(src);
          int i0 = (int)fi;
          double frac = src - fi;
          double s = 0.0;
          #pragma unroll
          for (int k = 0; k < 4; k++) {
            int iy = min(max(i0 + k - 1, 0), ph - 1);
            s += cubicw(frac - (double)(k - 1)) * qs[(j * ph + iy) * ph + x];
          }
          tt[i] = s;
        }
        __syncthreads();
        for (int i = tid; i < 8 * 256; i += 256) {
          int ox = i & 15; int oy = (i >> 4) & 15; int j = i >> 8;
          double src = ((double)ox + 0.5) * scale - 0.5;
          double fi = floor(src);
          int i0 = (int)fi;
          double frac = src - fi;
          double s = 0.0;
          #pragma unroll
          for (int k = 0; k < 4; k++) {
            int ix = min(max(i0 + k - 1, 0), ph - 1);
            s += cubicw(frac - (double)(k - 1)) * tt[(j * 16 + oy) * ph + ix];
          }
          q[(b * NC + c0 + j) * 256 + oy * 16 + ox] = s;
        }
        __syncthreads();   // lds reused next phase
      }
    }
    gridbar(&bars[bar_i++]);

    // ---------- phi: 0.5*x + 0.5*(conv3x3(x)+b), residual + loss ----------
    {
      double* simg = lds;                 // [32][16][16] = 64 KB
      int b = bid >> 2, co0 = (bid & 3) * 8;
      const double* qb = q + b * NC * 256;
      for (int i = tid; i < NC * 256; i += 256) simg[i] = qb[i];
      __syncthreads();
      int x = tid & 15, y = tid >> 4;
      double acc[8];
      #pragma unroll
      for (int j = 0; j < 8; j++) acc[j] = 0.0;
      const float* w = phi_w + pis[si] * NC * NC * 9;
      for (int ci = 0; ci < NC; ci++) {
        double wv[9];
        #pragma unroll
        for (int ky = 0; ky < 3; ky++) {
          int yy = y + ky - 1;
          #pragma unroll
          for (int kx = 0; kx < 3; kx++) {
            int xx = x + kx - 1;
            wv[ky * 3 + kx] = (yy >= 0 && yy < NH && xx >= 0 && xx < NW)
                              ? simg[ci * 256 + yy * 16 + xx] : 0.0;
          }
        }
        #pragma unroll
        for (int j = 0; j < 8; j++) {
          const float* wp = w + ((co0 + j) * NC + ci) * 9;  // uniform -> s_loads
          double a = acc[j];
          #pragma unroll
          for (int k = 0; k < 9; k++) a += wv[k] * (double)wp[k];
          acc[j] = a;
        }
      }
      double lsum = 0.0;
      #pragma unroll
      for (int j = 0; j < 8; j++) {
        int co = co0 + j;
        int i = co * 256 + tid;
        int gi = b * NC * 256 + i;
        double val = simg[i] * 0.5 + (acc[j] + (double)(phi_b[pis[si] * NC + co])) * 0.5;
        double zr = z_res[gi] - val;
        z_res[gi] = zr;
        if (si == 4) out_zhat[gi] = (float)((double)z[gi] - zr);
        lsum += zr * zr;   // z_hat - z == -z_res
      }
      __syncthreads();               // simg contents consumed
      double* red = simg;            // reuse LDS for reduction
      red[tid] = lsum; __syncthreads();
      for (int s = 128; s > 0; s >>= 1) {
        if (tid < s) red[tid] += red[tid + s];
        __syncthreads();
      }
      if (tid == 0) atomicAdd(loss_d, red[0]);
    }
    gridbar(&bars[bar_i++]);
  }

  if (bid == 0 && tid == 0) {
    double tot = atomicAdd(loss_d, 0.0);   // atomic read past stale caches
    *out_loss = (float)(tot * (1.25 / (5.0 * (double)NTOT)));
  }
}

extern "C" void kernel_launch(void* const* d_in, const int* in_sizes, int n_in,
                              void* d_out, int out_size, void* d_ws, size_t ws_size,
                              hipStream_t stream) {
  const float* z     = (const float*)d_in[0];   // [64,32,16,16]
  const float* emb   = (const float*)d_in[1];   // [4096,32]
  const float* phi_w = (const float*)d_in[2];   // [4,32,32,3,3]
  const float* phi_b = (const float*)d_in[3];   // [4,32]

  float* out      = (float*)d_out;
  float* out_zhat = out;
  float* out_loss = out + NTOT;
  float* out_idx  = out + NTOT + 1; // [64,341] as floats

  double* ws     = (double*)d_ws;
  double* z_res  = ws;                       // 524288 f64
  double* q      = z_res + NTOT;             // 524288 f64
  double* emb_sq = q + NTOT;                 // 4096 f64
  double* loss_d = emb_sq + NE;              // 1 f64
  float* emb_t   = (float*)(loss_d + 1);     // 131072 f32
  int* idx_ws    = (int*)(emb_t + NE * NC);  // 16384 int
  unsigned* bars = (unsigned*)(idx_ws + NB * 256);  // 16 one-shot barrier counters

  k_fused<<<GRID, TPB, 0, stream>>>(z, emb, phi_w, phi_b,
                                    z_res, q, emb_sq, loss_d,
                                    emb_t, idx_ws, bars,
                                    out_zhat, out_loss, out_idx);
}

// Round 9
// 929.726 us; speedup vs baseline: 1.2339x; 1.0725x over previous
//
#include <hip/hip_runtime.h>

#define NB 64
#define NC 32
#define NH 16
#define NW 16
#define NE 4096
#define NTOT (NB*NC*NH*NW)   // 524288
#define IDXW 341             // 1+4+16+64+256
#define GRID 256
#define TPB 1024
#define NBAR 16

__device__ __forceinline__ double cubicw(double x) {
  const double A = -0.75;
  x = fabs(x);
  if (x <= 1.0) return ((A + 2.0) * x - (A + 3.0)) * x * x + 1.0;
  if (x < 2.0)  return A * (((x - 5.0) * x + 8.0) * x - 4.0);
  return 0.0;
}

// One-shot software grid barrier (one counter per barrier, never reused).
// GRID=256 = #CUs: total residency capacity >= grid, all blocks co-resident.
__device__ __forceinline__ void gridbar(unsigned* bar) {
  __syncthreads();
  if (threadIdx.x == 0) {
    __threadfence();                       // release
    atomicAdd(bar, 1u);
    while (atomicAdd(bar, 0u) < (unsigned)GRID) __builtin_amdgcn_s_sleep(2);
    __threadfence();                       // acquire
  }
  __syncthreads();
}

__global__ __launch_bounds__(TPB, 4) void k_fused(
    const float* __restrict__ z, const float* __restrict__ emb,
    const float* __restrict__ phi_w, const float* __restrict__ phi_b,
    double* __restrict__ z_res, double* __restrict__ q,
    double* __restrict__ emb_sq, double* __restrict__ loss_d,
    float* __restrict__ emb_t, int* __restrict__ idx_ws,
    unsigned* __restrict__ bars,
    float* __restrict__ out_zhat, float* __restrict__ out_loss,
    float* __restrict__ out_idx)
{
  __shared__ double lds[8192];   // 64 KB scratch, reused per phase
  const int tid = threadIdx.x;
  const int bid = blockIdx.x;

  // Poisoned (0xAA) barrier counters: idempotent CAS-init by every block.
  if (tid < NBAR) atomicCAS(&bars[tid], 0xAAAAAAAAu, 0u);
  __syncthreads();
  int bar_i = 0;

  // ---------- setup: z_res init + emb transpose + emb_sq ----------
  for (int i = bid * TPB + tid; i < NTOT; i += GRID * TPB)
    z_res[i] = (double)z[i];
  if (bid == 0 && tid == 0) *loss_d = 0.0;
  if (bid < 64) {
    float* tile = (float*)lds;            // [64][33]
    int e0 = bid * 64;
    for (int t = tid; t < 2048; t += TPB) {
      int el = t >> 5, c = t & 31;
      tile[el * 33 + c] = emb[(e0 + el) * NC + c];
    }
    __syncthreads();
    for (int t = tid; t < 2048; t += TPB) {
      int c = t >> 6, ep = t & 63;
      emb_t[c * NE + e0 + ep] = tile[ep * 33 + c];
    }
    if (tid < 64) {
      const float* tr = &tile[tid * 33];
      double s = 0.0;
      #pragma unroll
      for (int j = 0; j < 8; j++)
        s += (double)tr[4*j]*tr[4*j] + (double)tr[4*j+1]*tr[4*j+1]
           + (double)tr[4*j+2]*tr[4*j+2] + (double)tr[4*j+3]*tr[4*j+3];
      emb_sq[e0 + tid] = s;
    }
  }
  gridbar(&bars[bar_i++]);

  const int phs[5]  = {1, 2, 4, 8, 16};
  // ticks = np.linspace(1/12, 11/12, 4) f64: si=2 real-arithmetic tie breaks
  // to pi=2 via 2-ulp linspace rounding (verified by exact mantissa calc).
  const int pis[5]  = {0, 1, 2, 2, 3};
  const int offs[5] = {0, 1, 5, 21, 85};

  for (int si = 0; si < 5; si++) {
    const int ph = phs[si], f = NH / ph;
    const int idx_off = offs[si];

    // ---------- argmin (fused area-pool, fp64 distances) ----------
    {
      double* rv = lds;                   // [8][32]
      double* wd = rv + 8 * NC;           // [16][8]
      int*    wi = (int*)(wd + 128);      // [16][8]
      int nchunks = (NB * ph * ph) >> 3;  // rows / 8
      for (int chunk = bid; chunk < nchunks; chunk += GRID) {
        int row0 = chunk * 8;
        if (tid < 256) {
          int j = tid >> 5, c = tid & 31;
          int n = row0 + j;
          int x = n % ph, y = (n / ph) % ph, b = n / (ph * ph);
          const double* base = z_res + (((b * NC + c) * NH) + y * f) * NW + x * f;
          double s = 0.0;
          for (int dy = 0; dy < f; dy++)
            for (int dx = 0; dx < f; dx++) s += base[dy * NW + dx];
          rv[j * NC + c] = s / (double)(f * f);
        }
        __syncthreads();
        double best[8]; int bidx[8];
        #pragma unroll
        for (int j = 0; j < 8; j++) { best[j] = 1e300; bidx[j] = 0; }
        #pragma unroll
        for (int pass = 0; pass < 2; pass++) {   // 1024 threads x 2 entries x 2 passes
          int e0 = pass * 2048 + tid * 2;
          double acc[8][2];
          #pragma unroll
          for (int j = 0; j < 8; j++) { acc[j][0] = 0.0; acc[j][1] = 0.0; }
          #pragma unroll 4
          for (int k = 0; k < NC; k++) {
            float2 e2 = *(const float2*)(emb_t + k * NE + e0);  // coalesced 8B/lane
            double d0 = e2.x, d1 = e2.y;
            #pragma unroll
            for (int j = 0; j < 8; j++) {
              double rj = rv[j * NC + k];
              acc[j][0] += rj * d0; acc[j][1] += rj * d1;
            }
          }
          #pragma unroll
          for (int v = 0; v < 2; v++) {      // ascending e per thread
            double esq = emb_sq[e0 + v];
            #pragma unroll
            for (int j = 0; j < 8; j++) {
              double d = esq - 2.0 * acc[j][v];
              if (d < best[j]) { best[j] = d; bidx[j] = e0 + v; }
            }
          }
        }
        #pragma unroll
        for (int j = 0; j < 8; j++) {
          double d = best[j]; int bi2 = bidx[j];
          #pragma unroll
          for (int off = 32; off >= 1; off >>= 1) {
            double od = __shfl_xor(d, off, 64);
            int oi = __shfl_xor(bi2, off, 64);
            if (od < d || (od == d && oi < bi2)) { d = od; bi2 = oi; }
          }
          best[j] = d; bidx[j] = bi2;
        }
        int wave = tid >> 6, lane = tid & 63;
        if (lane == 0) {
          #pragma unroll
          for (int j = 0; j < 8; j++) { wd[wave * 8 + j] = best[j]; wi[wave * 8 + j] = bidx[j]; }
        }
        __syncthreads();
        if (tid < 8) {
          double d = wd[tid]; int bi2 = wi[tid];
          #pragma unroll
          for (int w2 = 1; w2 < 16; w2++) {
            double od = wd[w2 * 8 + tid]; int oi = wi[w2 * 8 + tid];
            if (od < d || (od == d && oi < bi2)) { d = od; bi2 = oi; }
          }
          int n = row0 + tid;
          idx_ws[n] = bi2;
          int x = n % ph, y = (n / ph) % ph, b = n / (ph * ph);
          out_idx[b * IDXW + idx_off + y * ph + x] = (float)bi2;
        }
        __syncthreads();   // rv/wd/wi reused next chunk iteration
      }
    }
    gridbar(&bars[bar_i++]);

    // ---------- upsample: gather + bicubic H + W (8 channels per block) ----------
    {
      int b = bid >> 2, c0 = (bid & 3) * 8;
      if (ph == 16) {
        for (int i = tid; i < 8 * 256; i += TPB) {
          int j = i >> 8, rem = i & 255;
          q[(b * NC + c0 + j) * 256 + rem] = (double)emb[idx_ws[b * 256 + rem] * NC + c0 + j];
        }
      } else {
        double* qs = lds;                  // [8][ph][ph]
        double* tt = qs + 8 * ph * ph;     // [8][16][ph]
        for (int i = tid; i < 8 * ph * ph; i += TPB) {
          int j = i / (ph * ph), rem = i % (ph * ph);
          int y = rem / ph, x = rem % ph;
          qs[i] = (double)emb[idx_ws[(b * ph + y) * ph + x] * NC + c0 + j];
        }
        __syncthreads();
        double scale = (double)ph / 16.0;
        for (int i = tid; i < 8 * 16 * ph; i += TPB) {
          int x = i % ph; int oy = (i / ph) % 16; int j = i / (16 * ph);
          double src = ((double)oy + 0.5) * scale - 0.5;
          double fi = floor(src);
          int i0 = (int)fi;
          double frac = src - fi;
          double s = 0.0;
          #pragma unroll
          for (int k = 0; k < 4; k++) {
            int iy = min(max(i0 + k - 1, 0), ph - 1);
            s += cubicw(frac - (double)(k - 1)) * qs[(j * ph + iy) * ph + x];
          }
          tt[i] = s;
        }
        __syncthreads();
        for (int i = tid; i < 8 * 256; i += TPB) {
          int ox = i & 15; int oy = (i >> 4) & 15; int j = i >> 8;
          double src = ((double)ox + 0.5) * scale - 0.5;
          double fi = floor(src);
          int i0 = (int)fi;
          double frac = src - fi;
          double s = 0.0;
          #pragma unroll
          for (int k = 0; k < 4; k++) {
            int ix = min(max(i0 + k - 1, 0), ph - 1);
            s += cubicw(frac - (double)(k - 1)) * tt[(j * 16 + oy) * ph + ix];
          }
          q[(b * NC + c0 + j) * 256 + oy * 16 + ox] = s;
        }
        __syncthreads();
      }
    }
    gridbar(&bars[bar_i++]);

    // ---------- phi: 0.5*x + 0.5*(conv3x3(x)+b), residual + loss ----------
    {
      double* simg = lds;                 // [32][16][16] = 64 KB
      int b = bid >> 2, co0 = (bid & 3) * 8;
      int pix = tid & 255, sub = tid >> 8;   // 4 subs x 2 co = 8 co per block
      const double* qb = q + b * NC * 256;
      for (int i = tid; i < NC * 256; i += TPB) simg[i] = qb[i];
      __syncthreads();
      int x = pix & 15, y = pix >> 4;
      double acc[2] = {0.0, 0.0};
      const float* w = phi_w + pis[si] * NC * NC * 9;
      for (int ci = 0; ci < NC; ci++) {
        double wv[9];
        #pragma unroll
        for (int ky = 0; ky < 3; ky++) {
          int yy = y + ky - 1;
          #pragma unroll
          for (int kx = 0; kx < 3; kx++) {
            int xx = x + kx - 1;
            wv[ky * 3 + kx] = (yy >= 0 && yy < NH && xx >= 0 && xx < NW)
                              ? simg[ci * 256 + yy * 16 + xx] : 0.0;
          }
        }
        #pragma unroll
        for (int j = 0; j < 2; j++) {
          const float* wp = w + ((co0 + sub * 2 + j) * NC + ci) * 9;  // wave-uniform
          double a = acc[j];
          #pragma unroll
          for (int k = 0; k < 9; k++) a += wv[k] * (double)wp[k];
          acc[j] = a;
        }
      }
      double lsum = 0.0;
      #pragma unroll
      for (int j = 0; j < 2; j++) {
        int co = co0 + sub * 2 + j;
        int i = co * 256 + pix;
        int gi = b * NC * 256 + i;
        double val = simg[i] * 0.5 + (acc[j] + (double)(phi_b[pis[si] * NC + co])) * 0.5;
        double zr = z_res[gi] - val;
        z_res[gi] = zr;
        if (si == 4) out_zhat[gi] = (float)((double)z[gi] - zr);
        lsum += zr * zr;   // z_hat - z == -z_res
      }
      __syncthreads();               // simg contents consumed
      double* red = simg;            // reuse LDS for reduction
      red[tid] = lsum; __syncthreads();
      for (int s = 512; s > 0; s >>= 1) {
        if (tid < s) red[tid] += red[tid + s];
        __syncthreads();
      }
      if (tid == 0) atomicAdd(loss_d, red[0]);
    }
    gridbar(&bars[bar_i++]);
  }

  if (bid == 0 && tid == 0) {
    double tot = atomicAdd(loss_d, 0.0);   // atomic read past stale caches
    *out_loss = (float)(tot * (1.25 / (5.0 * (double)NTOT)));
  }
}

extern "C" void kernel_launch(void* const* d_in, const int* in_sizes, int n_in,
                              void* d_out, int out_size, void* d_ws, size_t ws_size,
                              hipStream_t stream) {
  const float* z     = (const float*)d_in[0];   // [64,32,16,16]
  const float* emb   = (const float*)d_in[1];   // [4096,32]
  const float* phi_w = (const float*)d_in[2];   // [4,32,32,3,3]
  const float* phi_b = (const float*)d_in[3];   // [4,32]

  float* out      = (float*)d_out;
  float* out_zhat = out;
  float* out_loss = out + NTOT;
  float* out_idx  = out + NTOT + 1; // [64,341] as floats

  double* ws     = (double*)d_ws;
  double* z_res  = ws;                       // 524288 f64
  double* q      = z_res + NTOT;             // 524288 f64
  double* emb_sq = q + NTOT;                 // 4096 f64
  double* loss_d = emb_sq + NE;              // 1 f64
  float* emb_t   = (float*)(loss_d + 1);     // 131072 f32
  int* idx_ws    = (int*)(emb_t + NE * NC);  // 16384 int
  unsigned* bars = (unsigned*)(idx_ws + NB * 256);  // 16 one-shot barrier counters

  k_fused<<<GRID, TPB, 0, stream>>>(z, emb, phi_w, phi_b,
                                    z_res, q, emb_sq, loss_d,
                                    emb_t, idx_ws, bars,
                                    out_zhat, out_loss, out_idx);
}